// Round 8
// baseline (145.512 us; speedup 1.0000x reference)
//
#include <hip/hip_runtime.h>
#include <math.h>

#define DEVI __device__ __forceinline__

constexpr int B = 2, P = 16, G = 128, E = 96, N = 128, CO = 2;

DEVI float lrelu(float x) { return x > 0.f ? x : 0.01f * x; }

// ---- workspace layout (floats) ----
// U1: [b][g][p][n]   V1: [b][g][n][e]   (raw GEMM outputs; biases added in post2)
constexpr int OFF_U1     = 0;                       // 524288
constexpr int OFF_V1     = OFF_U1 + 524288;         // 3145728
constexpr int OFF_MAXPU0 = OFF_V1 + 3145728;        // 32768
constexpr int OFF_MAXEV0 = OFF_MAXPU0 + 32768;      // 32768
constexpr int OFF_MP110  = OFF_MAXEV0 + 32768;      // 32768 (== me011)
constexpr int OFF_MG110  = OFF_MP110 + 32768;       // 4096
constexpr int OFF_S001A  = OFF_MG110 + 4096;        // 24576 (== mg011)
constexpr int OFF_RMP    = OFF_S001A + 24576;       // 1024
constexpr int OFF_RMG    = OFF_RMP + 1024;          // 128
constexpr int OFF_RME    = OFF_RMG + 128;           // 512
constexpr int OFF_RMG011 = OFF_RME + 512;           // 384
constexpr int OFF_M110   = OFF_RMG011 + 384;        // 4096
constexpr int OFF_M011E  = OFF_M110 + 4096;         // 24576
constexpr int OFF_S001B  = OFF_M011E + 24576;       // 24576
constexpr int OFF_WT     = OFF_S001B + 24576;       // 5*16384
// wT[m][c][n]: m0=W1[0]^T, m1=(W1[1]+W1[5])^T, m2=W1[2]^T, m3=W1[3]^T, m4=(W1[4]+W1[6])^T

// ---------------------------------------------------------------------------
// K1: fused layer 0, one block per (b,n) [R4/R7-proven] + W1 transpose tail.
__global__ void __launch_bounds__(256) k_layer0(
    const float* __restrict__ x110, const float* __restrict__ x011,
    const float* __restrict__ x001,
    const float* __restrict__ W0_110, const float* __restrict__ b0_110,
    const float* __restrict__ W0_011, const float* __restrict__ b0_011,
    const float* __restrict__ W0_001, const float* __restrict__ b0_001,
    const float* __restrict__ W1,
    float* __restrict__ maxpU0g, float* __restrict__ maxeV0g,
    float* __restrict__ mp110, float* __restrict__ mg110,
    float* __restrict__ s001a,
    float* __restrict__ rmpG, float* __restrict__ rmgG,
    float* __restrict__ rmeG, float* __restrict__ rmg011G,
    float* __restrict__ wT) {
  __shared__ float xs[4 * 16 * 128];
  __shared__ float v0[128 * 97];
  __shared__ float u0[16 * 128];
  __shared__ float rmp[512], rmgS[64], rme[256], rmg011L[192];
  __shared__ float mpu[128], mev[128], part[256];
  const int bn = blockIdx.x, b = bn >> 7, n = bn & 127, tid = threadIdx.x;

  {
    const float4* xsrc = (const float4*)(x110 + (size_t)b * 8192);
    float4* xdst = (float4*)xs;
#pragma unroll
    for (int k = 0; k < 8; k++) xdst[tid + k * 256] = xsrc[tid + k * 256];
  }
  __syncthreads();
  for (int i = tid; i < 512; i += 256) {
    int c = i >> 7, g = i & 127;
    float m = -INFINITY;
    for (int p = 0; p < P; p++) m = fmaxf(m, xs[(c * 16 + p) * 128 + g]);
    rmp[i] = m;
  }
  if (tid < 64) {
    int c = tid >> 4, p = tid & 15;
    float m = -INFINITY;
    for (int g = 0; g < G; g++) m = fmaxf(m, xs[(c * 16 + p) * 128 + g]);
    rmgS[tid] = m;
  }
  {
    int c = tid >> 7, g = tid & 127;
    const float4* r = (const float4*)(x011 + ((size_t)(b * 2 + c) * 128 + g) * 96);
    float m = -INFINITY;
#pragma unroll
    for (int j = 0; j < 24; j++) {
      float4 v = r[j];
      m = fmaxf(m, fmaxf(fmaxf(v.x, v.y), fmaxf(v.z, v.w)));
    }
    rme[tid] = m;
  }
  if (tid < 192) {
    int c = tid / 96, e = tid % 96;
    const float* pp = x011 + ((size_t)(b * 2 + c) * 128) * 96 + e;
    float m = -INFINITY;
    for (int g = 0; g < G; g++) m = fmaxf(m, pp[g * 96]);
    rmg011L[tid] = m;
  }
  __syncthreads();
  float w0[4], w1[4], w2[4];
#pragma unroll
  for (int cc = 0; cc < 4; cc++) {
    w0[cc] = W0_110[n * 4 + cc];
    w1[cc] = W0_110[512 + n * 4 + cc];
    w2[cc] = W0_110[1024 + n * 4 + cc];
  }
  float we0 = W0_011[512 + n * 2], we1 = W0_011[512 + n * 2 + 1];
  float bu = b0_110[n] + b0_110[128 + n] + b0_110[256 + n] + b0_011[256 + n];
  float vw00 = W0_011[n * 2], vw01 = W0_011[n * 2 + 1];
  float vw10 = W0_011[256 + n * 2], vw11 = W0_011[256 + n * 2 + 1];
  float w001 = W0_001[n];
  float bv = b0_011[n] + b0_011[128 + n] + b0_001[n];

#pragma unroll
  for (int k = 0; k < 8; k++) {
    int i = tid + k * 256, p = i >> 7, g = i & 127;
    float acc = bu + we0 * rme[g] + we1 * rme[128 + g];
#pragma unroll
    for (int cc = 0; cc < 4; cc++)
      acc += w0[cc] * xs[(cc * 16 + p) * 128 + g] + w1[cc] * rmp[cc * 128 + g]
           + w2[cc] * rmgS[cc * 16 + p];
    u0[i] = acc;
  }
  {
    const float* xa = x011 + (size_t)(b * 2) * 12288;
    const float* xb = xa + 12288;
    const float* xc = x001 + b * 96;
    for (int k = 0; k < 48; k++) {
      int i = tid + k * 256;
      int g = i / 96, e = i - g * 96;
      float val = bv + vw00 * xa[i] + vw01 * xb[i]
                + vw10 * rmg011L[e] + vw11 * rmg011L[96 + e] + w001 * xc[e];
      v0[g * 97 + e] = val;
    }
  }
  __syncthreads();
  if (tid < 128) {
    float m = -INFINITY;
    for (int p = 0; p < P; p++) m = fmaxf(m, u0[p * 128 + tid]);
    mpu[tid] = m;
    maxpU0g[bn * 128 + tid] = m;
  }
  {
    int g = tid & 127, h = tid >> 7;
    const float* r = &v0[g * 97 + h * 48];
    float m = -INFINITY;
    for (int j = 0; j < 48; j++) m = fmaxf(m, r[j]);
    part[tid] = m;
  }
  __syncthreads();
  if (tid < 128) {
    float m = fmaxf(part[tid], part[128 + tid]);
    mev[tid] = m;
    maxeV0g[bn * 128 + tid] = m;
    mp110[bn * 128 + tid] = lrelu(mpu[tid] + m);
  }
  __syncthreads();
  {
    int p = tid >> 4, ch = tid & 15;
    float m = -INFINITY;
    for (int g = ch * 8; g < ch * 8 + 8; g++)
      m = fmaxf(m, u0[p * 128 + g] + mev[g]);
    part[tid] = m;
  }
  if (tid < 96) {
    float m = -INFINITY;
    for (int g = 0; g < G; g++) m = fmaxf(m, mpu[g] + v0[g * 97 + tid]);
    s001a[bn * 96 + tid] = lrelu(m);
  }
  __syncthreads();
  if (tid < 16) {
    float m = -INFINITY;
    for (int ch = 0; ch < 16; ch++) m = fmaxf(m, part[tid * 16 + ch]);
    mg110[bn * 16 + tid] = lrelu(m);
  }
  if (n == 0) {
    for (int i = tid; i < 512; i += 256) rmpG[b * 512 + i] = rmp[i];
    if (tid < 64) rmgG[b * 64 + tid] = rmgS[tid];
    rmeG[b * 256 + tid] = rme[tid];
    if (tid < 192) rmg011G[b * 192 + tid] = rmg011L[tid];
  }
  // ---- W1 transpose/fold tail: wT[m][c][n] ----
  {
    const int gt = bn * 256 + tid;
#pragma unroll
    for (int it = 0; it < 2; it++) {
      int idx = gt + it * 65536;
      if (idx < 81920) {
        int m = idx >> 14, r = idx & 16383;
        int c = r >> 7, nn = r & 127;
        float v;
        if (m == 0)      v = W1[nn * 128 + c];
        else if (m == 1) v = W1[16384 + nn * 128 + c] + W1[5 * 16384 + nn * 128 + c];
        else if (m == 2) v = W1[2 * 16384 + nn * 128 + c];
        else if (m == 3) v = W1[3 * 16384 + nn * 128 + c];
        else             v = W1[4 * 16384 + nn * 128 + c] + W1[6 * 16384 + nn * 128 + c];
        wT[idx] = v;
      }
    }
  }
}

// ---------------------------------------------------------------------------
// K2: layer 1 PURE GEMMs. One block per (b,g), 512 threads. [R7-proven]
__global__ void __launch_bounds__(512) k_layer1c(
    const float* __restrict__ x110, const float* __restrict__ x011,
    const float* __restrict__ x001,
    const float* __restrict__ W0_110, const float* __restrict__ b0_110,
    const float* __restrict__ W0_011, const float* __restrict__ b0_011,
    const float* __restrict__ W0_001, const float* __restrict__ b0_001,
    const float* __restrict__ maxpU0g, const float* __restrict__ maxeV0g,
    const float* __restrict__ rmpG, const float* __restrict__ rmgG,
    const float* __restrict__ rmeG, const float* __restrict__ rmg011G,
    const float* __restrict__ wT,
    float* __restrict__ U1, float* __restrict__ V1) {
  __shared__ float s110c[128 * 16];
  __shared__ float s011c[128 * 96];
  __shared__ float W0L110[1536], W0L011[768], W0L001[128];
  __shared__ float busum[128], bvsum[128], mpu[128], mev[128];
  __shared__ float x011row[192], rmg011s[192], x001s[96];
  __shared__ float x110col[64], rmg110p[64], rmp4[4], rme2[2];
  const int blk = blockIdx.x;
  const int b = blk >> 7, g = blk & 127;
  const int tid = threadIdx.x;

  for (int i = tid; i < 1536; i += 512) W0L110[i] = W0_110[i];
  for (int i = tid; i < 768; i += 512) W0L011[i] = W0_011[i];
  if (tid < 128) {
    W0L001[tid] = W0_001[tid];
    busum[tid] = b0_110[tid] + b0_110[128 + tid] + b0_110[256 + tid]
               + b0_011[256 + tid];
    bvsum[tid] = b0_011[tid] + b0_011[128 + tid] + b0_001[tid];
    mpu[tid] = maxpU0g[(b * 128 + tid) * 128 + g];
    mev[tid] = maxeV0g[(b * 128 + tid) * 128 + g];
  } else if (tid >= 256 && tid < 448) {
    int i = tid - 256;
    int c = i / 96, e = i % 96;
    x011row[i] = x011[((size_t)(b * 2 + c) * 128 + g) * 96 + e];
    rmg011s[i] = rmg011G[b * 192 + i];
  } else if (tid >= 448 && tid < 512) {
    int i = tid - 448;
    int c = i >> 4, p = i & 15;
    x110col[i] = x110[((size_t)(b * 4 + c) * 16 + p) * 128 + g];
    rmg110p[i] = rmgG[b * 64 + i];
  } else if (tid >= 128 && tid < 224) {
    x001s[tid - 128] = x001[b * 96 + tid - 128];
  } else if (tid >= 224 && tid < 228) {
    rmp4[tid - 224] = rmpG[(b * 4 + tid - 224) * 128 + g];
  } else if (tid >= 228 && tid < 230) {
    rme2[tid - 228] = rmeG[(b * 2 + tid - 228) * 128 + g];
  }
  __syncthreads();

#pragma unroll
  for (int k = 0; k < 4; k++) {
    int i = tid + k * 512, c = i >> 4, p = i & 15;
    float acc = busum[c] + W0L011[512 + c * 2] * rme2[0]
              + W0L011[512 + c * 2 + 1] * rme2[1];
#pragma unroll
    for (int cc = 0; cc < 4; cc++)
      acc += W0L110[c * 4 + cc] * x110col[cc * 16 + p]
           + W0L110[512 + c * 4 + cc] * rmp4[cc]
           + W0L110[1024 + c * 4 + cc] * rmg110p[cc * 16 + p];
    s110c[i] = lrelu(acc + mev[c]);
  }
  for (int k = 0; k < 24; k++) {
    int i = tid + k * 512;
    int c = i / 96, e = i - c * 96;
    float v = bvsum[c]
            + W0L011[c * 2] * x011row[e] + W0L011[c * 2 + 1] * x011row[96 + e]
            + W0L011[256 + c * 2] * rmg011s[e]
            + W0L011[256 + c * 2 + 1] * rmg011s[96 + e]
            + W0L001[c] * x001s[e];
    s011c[i] = lrelu(v + mpu[c]);
  }
  __syncthreads();

  const float* w0T = wT;
  const float* w3T = wT + 3 * 16384;

  {
    int n = tid & 127, ph = tid >> 7;
    float a[4] = {0.f, 0.f, 0.f, 0.f};
    for (int c = 0; c < 128; c++) {
      float w0v = w0T[c * 128 + n];
      float4 s = *(const float4*)&s110c[c * 16 + ph * 4];
      a[0] += w0v * s.x; a[1] += w0v * s.y; a[2] += w0v * s.z; a[3] += w0v * s.w;
    }
    float* dst = U1 + ((size_t)((b * 128 + g) * 16 + ph * 4)) * 128 + n;
#pragma unroll
    for (int j = 0; j < 4; j++) dst[j * 128] = a[j];
  }
  {
    int n0 = (tid >> 3) * 2, e0 = (tid & 7) * 12;
    float4 aA[3], aB[3];
#pragma unroll
    for (int k = 0; k < 3; k++) {
      aA[k] = make_float4(0.f, 0.f, 0.f, 0.f);
      aB[k] = make_float4(0.f, 0.f, 0.f, 0.f);
    }
    for (int c = 0; c < 128; c++) {
      float2 wv = *(const float2*)&w3T[c * 128 + n0];
      float4 s0 = *(const float4*)&s011c[c * 96 + e0];
      float4 s1 = *(const float4*)&s011c[c * 96 + e0 + 4];
      float4 s2 = *(const float4*)&s011c[c * 96 + e0 + 8];
      aA[0].x += wv.x * s0.x; aA[0].y += wv.x * s0.y;
      aA[0].z += wv.x * s0.z; aA[0].w += wv.x * s0.w;
      aA[1].x += wv.x * s1.x; aA[1].y += wv.x * s1.y;
      aA[1].z += wv.x * s1.z; aA[1].w += wv.x * s1.w;
      aA[2].x += wv.x * s2.x; aA[2].y += wv.x * s2.y;
      aA[2].z += wv.x * s2.z; aA[2].w += wv.x * s2.w;
      aB[0].x += wv.y * s0.x; aB[0].y += wv.y * s0.y;
      aB[0].z += wv.y * s0.z; aB[0].w += wv.y * s0.w;
      aB[1].x += wv.y * s1.x; aB[1].y += wv.y * s1.y;
      aB[1].z += wv.y * s1.z; aB[1].w += wv.y * s1.w;
      aB[2].x += wv.y * s2.x; aB[2].y += wv.y * s2.y;
      aB[2].z += wv.y * s2.z; aB[2].w += wv.y * s2.w;
    }
    float* dA = V1 + ((size_t)((b * 128 + g) * 128 + n0)) * 96 + e0;
    float* dB = dA + 96;
#pragma unroll
    for (int k = 0; k < 3; k++) {
      *(float4*)(dA + k * 4) = aA[k];
      *(float4*)(dB + k * 4) = aB[k];
    }
  }
}

// ---------------------------------------------------------------------------
// K3: streaming g-reduction. grid = (b, n-chunk of 8) = 32 blocks, 256 thr.
__global__ void __launch_bounds__(256) k_post2(
    const float* __restrict__ U1, const float* __restrict__ V1,
    const float* __restrict__ s001a, const float* __restrict__ mp110,
    const float* __restrict__ mg110,
    const float* __restrict__ wT, const float* __restrict__ b1,
    float* __restrict__ m110, float* __restrict__ m011e,
    float* __restrict__ s001b) {
  constexpr int GS = 8;
  __shared__ float Vt[GS][8][100];         // 25.6KB  (g-step, nn, e) padded
  __shared__ float Ut[GS][16][9];          // 4.6KB   (g-step, p, nn) padded
  __shared__ float bfL[8][128];            // 4KB
  __shared__ float egL[8][96];
  __shared__ float cpL[8][16];
  __shared__ float partE[GS][8][4];
  __shared__ float mxeV[GS][8], mxpU[GS][8];
  __shared__ float bbL[8], bvL[8];
  const int blk = blockIdx.x, b = blk >> 4, nc = blk & 15, n0 = nc * 8;
  const int tid = threadIdx.x;
  const float* w15T = wT + 16384;
  const float* w2T  = wT + 2 * 16384;
  const float* w46T = wT + 4 * 16384;

  if (tid < 8) {
    int n = n0 + tid;
    bbL[tid] = b1[n] + b1[128 + n] + b1[256 + n] + b1[640 + n];
    bvL[tid] = b1[384 + n] + b1[512 + n] + b1[768 + n];
  }
  {  // bf[nn][g] = sum_c w15T[c][n] * mp110[b,c,g]
    int g = tid & 127, h = tid >> 7;
    float a0 = 0, a1 = 0, a2 = 0, a3 = 0;
    for (int c = 0; c < 128; c++) {
      float m = mp110[(b * 128 + c) * 128 + g];
      const float* wr = &w15T[c * 128 + n0 + h * 4];
      a0 += wr[0] * m; a1 += wr[1] * m; a2 += wr[2] * m; a3 += wr[3] * m;
    }
    bfL[h * 4 + 0][g] = a0; bfL[h * 4 + 1][g] = a1;
    bfL[h * 4 + 2][g] = a2; bfL[h * 4 + 3][g] = a3;
  }
#pragma unroll
  for (int k = 0; k < 3; k++) {  // eg[nn][e] = sum_c w46T[c][n] * s001a[b,c,e]
    int s = tid + k * 256;
    int nn = s / 96, e = s % 96;
    float acc = 0.f;
    for (int c = 0; c < 128; c++)
      acc += w46T[c * 128 + n0 + nn] * s001a[b * 12288 + c * 96 + e];
    egL[nn][e] = acc;
  }
  if (tid < 128) {               // cp[nn][p] = sum_c w2T[c][n] * mg110[b,c,p]
    int nn = tid >> 4, p = tid & 15;
    float acc = 0.f;
    for (int c = 0; c < 128; c++)
      acc += w2T[c * 128 + n0 + nn] * mg110[(b * 128 + c) * 16 + p];
    cpL[nn][p] = acc;
  }

  float accM110 = 0.f;
  float accSum[3] = {0.f, 0.f, 0.f};
  float accMax[3] = {-INFINITY, -INFINITY, -INFINITY};
  const size_t Ubase = (size_t)b * 128 * 16 * 128;
  const size_t Vbase = (size_t)b * 128 * 128 * 96;

  for (int go = 0; go < 128; go += GS) {
    __syncthreads();
#pragma unroll
    for (int k = 0; k < 24; k++) {         // stage V (+bv+eg)
      int i = tid + k * 256;
      int gs = i / 768, r = i % 768, nn = r / 96, e = r % 96;
      float v = V1[Vbase + ((size_t)(go + gs) * 128 + n0 + nn) * 96 + e];
      Vt[gs][nn][e] = v + bvL[nn] + egL[nn][e];
    }
#pragma unroll
    for (int k = 0; k < 4; k++) {          // stage U (+bb+cp+bf)
      int i = tid + k * 256;
      int gs = i >> 7, r = i & 127, p = r >> 3, nn = r & 7;
      float u = U1[Ubase + ((size_t)(go + gs) * 16 + p) * 128 + n0 + nn];
      Ut[gs][p][nn] = u + bbL[nn] + cpL[nn][p] + bfL[nn][go + gs];
    }
    __syncthreads();
    {                                      // partial max_e
      int gs = tid >> 5, nn = (tid >> 2) & 7, ec = tid & 3;
      float m = -INFINITY;
      for (int e = ec * 24; e < ec * 24 + 24; e++) m = fmaxf(m, Vt[gs][nn][e]);
      partE[gs][nn][ec] = m;
    }
    __syncthreads();
    if (tid < 64) {                        // finish maxes
      int gs = tid >> 3, nn = tid & 7;
      mxeV[gs][nn] = fmaxf(fmaxf(partE[gs][nn][0], partE[gs][nn][1]),
                           fmaxf(partE[gs][nn][2], partE[gs][nn][3]));
      float m = -INFINITY;
      for (int p = 0; p < 16; p++) m = fmaxf(m, Ut[gs][p][nn]);
      mxpU[gs][nn] = m;
    }
    __syncthreads();
    if (tid < 128) {                       // m110 accumulate
      int nn = tid >> 4, p = tid & 15;
#pragma unroll
      for (int gs = 0; gs < GS; gs++)
        accM110 += lrelu(Ut[gs][p][nn] + mxeV[gs][nn]);
    }
#pragma unroll
    for (int k = 0; k < 3; k++) {          // m011e / s001b accumulate
      int s = tid + k * 256;
      int nn = s / 96, e = s % 96;
#pragma unroll
      for (int gs = 0; gs < GS; gs++) {
        float pre = mxpU[gs][nn] + Vt[gs][nn][e];
        accSum[k] += lrelu(pre);
        accMax[k] = fmaxf(accMax[k], pre);
      }
    }
  }
  if (tid < 128) {
    int nn = tid >> 4, p = tid & 15;
    m110[(b * 128 + n0 + nn) * 16 + p] = accM110 * (1.f / G);
  }
#pragma unroll
  for (int k = 0; k < 3; k++) {
    int s = tid + k * 256;
    int nn = s / 96, e = s % 96;
    m011e[(b * 128 + n0 + nn) * 96 + e] = accSum[k] * (1.f / G);
    s001b[(b * 128 + n0 + nn) * 96 + e] = lrelu(accMax[k]);
  }
}

// ---------------------------------------------------------------------------
// K4: heads, LDS-staged (all global reads coalesced). One block per (b,o).
__global__ void __launch_bounds__(128) k_final(const float* __restrict__ m110,
                                               const float* __restrict__ m011e,
                                               const float* __restrict__ s001,
                                               const float* __restrict__ Wact,
                                               const float* __restrict__ bact,
                                               const float* __restrict__ Wcrit,
                                               const float* __restrict__ bcrit,
                                               float* __restrict__ out) {
  __shared__ float buf[128][97];           // 49.7KB staged rows
  __shared__ float m110s[128][17];         // 8.7KB
  __shared__ float sm011[N], sm001[N], sce1[E], sce[E], scp[P], srow[P], scol[E];
  const int bo = blockIdx.x;
  const int o = bo & 1, b = bo >> 1;
  const int t = threadIdx.x;

  // stage m110[b] + m011e[b] (coalesced)
#pragma unroll
  for (int k = 0; k < 16; k++) {
    int i = t + k * 128;
    m110s[i >> 4][i & 15] = m110[b * 2048 + i];
  }
  for (int k = 0; k < 96; k++) {
    int i = t + k * 128;
    buf[i / 96][i % 96] = m011e[b * 12288 + i];
  }
  __syncthreads();
  {  // sm011[n]
    float s = 0.f;
    for (int e = 0; e < E; e++) s += buf[t][e];
    sm011[t] = s * (1.f / E);
  }
  if (t < 96) {  // sce1[e] = sum_n wc1[n]*m011e[n][e]
    const float* wc1 = Wcrit + (1 * CO + o) * N;
    float c = 0.f;
    for (int n = 0; n < N; n++) c += wc1[n] * buf[n][t];
    sce1[t] = c;
  }
  __syncthreads();
  for (int k = 0; k < 96; k++) {  // restage buf = s001b
    int i = t + k * 128;
    buf[i / 96][i % 96] = s001[b * 12288 + i];
  }
  __syncthreads();
  {  // sm001[n]
    float s = 0.f;
    for (int e = 0; e < E; e++) s += buf[t][e];
    sm001[t] = s * (1.f / E);
  }
  if (t < 96) {  // sce[e]
    const float* wc2 = Wcrit + (2 * CO + o) * N;
    float c = 0.f;
    for (int n = 0; n < N; n++) c += wc2[n] * buf[n][t];
    sce[t] = sce1[t] + c + bcrit[CO + o] + bcrit[2 * CO + o];
  }
  __syncthreads();
  if (t < P) {  // actions + scp
    const float* wa0 = Wact + o * N;
    const float* wa1 = Wact + (1 * CO + o) * N;
    const float* wa2 = Wact + (2 * CO + o) * N;
    const float* wc0 = Wcrit + o * N;
    float a = 0.f, c = 0.f, aa = 0.f;
    for (int n = 0; n < N; n++) {
      float m = m110s[n][t];
      a += wa0[n] * m;
      c += wc0[n] * m;
      aa += wa1[n] * sm011[n] + wa2[n] * sm001[n];
    }
    float act = a + aa + bact[o] + bact[CO + o] + bact[2 * CO + o];
    out[(b * CO + o) * P + t] = lrelu(act);
    scp[t] = c + bcrit[o];
  }
  __syncthreads();
  if (t < P) {
    float m = -INFINITY;
    for (int e = 0; e < E; e++) m = fmaxf(m, lrelu(scp[t] + sce[e]));
    srow[t] = m;
  } else if (t < P + E) {
    int e = t - P;
    float m = -INFINITY;
    for (int p = 0; p < P; p++) m = fmaxf(m, lrelu(scp[p] + sce[e]));
    scol[e] = m;
  }
  __syncthreads();
  if (t == 0) {
    float v110 = 0.f, v011 = 0.f;
    for (int p = 0; p < P; p++) v110 += srow[p];
    for (int e = 0; e < E; e++) v011 += scol[e];
    out[B * CO * P + b * CO + o] = 2.f + v110 + 2.f * v011;
  }
}

extern "C" void kernel_launch(void* const* d_in, const int* in_sizes, int n_in,
                              void* d_out, int out_size, void* d_ws, size_t ws_size,
                              hipStream_t stream) {
  const float* x110   = (const float*)d_in[0];
  const float* x011   = (const float*)d_in[1];
  const float* x001   = (const float*)d_in[2];
  const float* W0_110 = (const float*)d_in[3];
  const float* b0_110 = (const float*)d_in[4];
  const float* W0_011 = (const float*)d_in[5];
  const float* b0_011 = (const float*)d_in[6];
  const float* W0_001 = (const float*)d_in[7];
  const float* b0_001 = (const float*)d_in[8];
  const float* W1     = (const float*)d_in[9];
  const float* b1     = (const float*)d_in[10];
  const float* Wact   = (const float*)d_in[11];
  const float* bact   = (const float*)d_in[12];
  const float* Wcrit  = (const float*)d_in[13];
  const float* bcrit  = (const float*)d_in[14];
  float* out = (float*)d_out;
  float* w = (float*)d_ws;

  float* U1     = w + OFF_U1;
  float* V1     = w + OFF_V1;
  float* maxpU0 = w + OFF_MAXPU0;
  float* maxeV0 = w + OFF_MAXEV0;
  float* mp110  = w + OFF_MP110;
  float* mg110  = w + OFF_MG110;
  float* s001a  = w + OFF_S001A;
  float* rmpG   = w + OFF_RMP;
  float* rmgG   = w + OFF_RMG;
  float* rmeG   = w + OFF_RME;
  float* rmg011 = w + OFF_RMG011;
  float* m110   = w + OFF_M110;
  float* m011e  = w + OFF_M011E;
  float* s001b  = w + OFF_S001B;
  float* wT     = w + OFF_WT;

  k_layer0<<<256, 256, 0, stream>>>(x110, x011, x001, W0_110, b0_110, W0_011,
                                    b0_011, W0_001, b0_001, W1,
                                    maxpU0, maxeV0, mp110, mg110, s001a,
                                    rmpG, rmgG, rmeG, rmg011, wT);
  k_layer1c<<<256, 512, 0, stream>>>(x110, x011, x001, W0_110, b0_110, W0_011,
                                     b0_011, W0_001, b0_001,
                                     maxpU0, maxeV0, rmpG, rmgG, rmeG, rmg011,
                                     wT, U1, V1);
  k_post2<<<32, 256, 0, stream>>>(U1, V1, s001a, mp110, mg110, wT, b1,
                                  m110, m011e, s001b);
  k_final<<<4, 128, 0, stream>>>(m110, m011e, s001b, Wact, bact, Wcrit, bcrit, out);
}

// Round 9
// 112.585 us; speedup vs baseline: 1.2925x; 1.2925x over previous
//
#include <hip/hip_runtime.h>
#include <math.h>

#define DEVI __device__ __forceinline__

constexpr int B = 2, P = 16, G = 128, E = 96, N = 128, CO = 2;

DEVI float lrelu(float x) { return x > 0.f ? x : 0.01f * x; }

// ---- workspace layout (floats) ----
// U1: [b][g][p][n]   V1: [b][g][n][e]   (raw GEMM outputs; biases added in post3)
constexpr int OFF_U1     = 0;                       // 524288
constexpr int OFF_V1     = OFF_U1 + 524288;         // 3145728
constexpr int OFF_MAXPU0 = OFF_V1 + 3145728;        // 32768
constexpr int OFF_MAXEV0 = OFF_MAXPU0 + 32768;      // 32768
constexpr int OFF_MP110  = OFF_MAXEV0 + 32768;      // 32768 (== me011)
constexpr int OFF_MG110  = OFF_MP110 + 32768;       // 4096
constexpr int OFF_S001A  = OFF_MG110 + 4096;        // 24576 (== mg011)
constexpr int OFF_RMP    = OFF_S001A + 24576;       // 1024
constexpr int OFF_RMG    = OFF_RMP + 1024;          // 128
constexpr int OFF_RME    = OFF_RMG + 128;           // 512
constexpr int OFF_RMG011 = OFF_RME + 512;           // 384
constexpr int OFF_M110   = OFF_RMG011 + 384;        // 4096
constexpr int OFF_M011E  = OFF_M110 + 4096;         // 24576
constexpr int OFF_S001B  = OFF_M011E + 24576;       // 24576
constexpr int OFF_WT     = OFF_S001B + 24576;       // 5*16384
constexpr int OFF_PART   = OFF_WT + 81920;          // 256*1664 = 425984
// part[b][nc][gc][1664]: [0:128)=pm110(nn*16+p), [128:896)=psum(nn*96+e), [896:1664)=pmax

// ---------------------------------------------------------------------------
// K1: fused layer 0, one block per (b,n) [R4..R8-proven] + W1 transpose tail.
__global__ void __launch_bounds__(256) k_layer0(
    const float* __restrict__ x110, const float* __restrict__ x011,
    const float* __restrict__ x001,
    const float* __restrict__ W0_110, const float* __restrict__ b0_110,
    const float* __restrict__ W0_011, const float* __restrict__ b0_011,
    const float* __restrict__ W0_001, const float* __restrict__ b0_001,
    const float* __restrict__ W1,
    float* __restrict__ maxpU0g, float* __restrict__ maxeV0g,
    float* __restrict__ mp110, float* __restrict__ mg110,
    float* __restrict__ s001a,
    float* __restrict__ rmpG, float* __restrict__ rmgG,
    float* __restrict__ rmeG, float* __restrict__ rmg011G,
    float* __restrict__ wT) {
  __shared__ float xs[4 * 16 * 128];
  __shared__ float v0[128 * 97];
  __shared__ float u0[16 * 128];
  __shared__ float rmp[512], rmgS[64], rme[256], rmg011L[192];
  __shared__ float mpu[128], mev[128], part[256];
  const int bn = blockIdx.x, b = bn >> 7, n = bn & 127, tid = threadIdx.x;

  {
    const float4* xsrc = (const float4*)(x110 + (size_t)b * 8192);
    float4* xdst = (float4*)xs;
#pragma unroll
    for (int k = 0; k < 8; k++) xdst[tid + k * 256] = xsrc[tid + k * 256];
  }
  __syncthreads();
  for (int i = tid; i < 512; i += 256) {
    int c = i >> 7, g = i & 127;
    float m = -INFINITY;
    for (int p = 0; p < P; p++) m = fmaxf(m, xs[(c * 16 + p) * 128 + g]);
    rmp[i] = m;
  }
  if (tid < 64) {
    int c = tid >> 4, p = tid & 15;
    float m = -INFINITY;
    for (int g = 0; g < G; g++) m = fmaxf(m, xs[(c * 16 + p) * 128 + g]);
    rmgS[tid] = m;
  }
  {
    int c = tid >> 7, g = tid & 127;
    const float4* r = (const float4*)(x011 + ((size_t)(b * 2 + c) * 128 + g) * 96);
    float m = -INFINITY;
#pragma unroll
    for (int j = 0; j < 24; j++) {
      float4 v = r[j];
      m = fmaxf(m, fmaxf(fmaxf(v.x, v.y), fmaxf(v.z, v.w)));
    }
    rme[tid] = m;
  }
  if (tid < 192) {
    int c = tid / 96, e = tid % 96;
    const float* pp = x011 + ((size_t)(b * 2 + c) * 128) * 96 + e;
    float m = -INFINITY;
    for (int g = 0; g < G; g++) m = fmaxf(m, pp[g * 96]);
    rmg011L[tid] = m;
  }
  __syncthreads();
  float w0[4], w1[4], w2[4];
#pragma unroll
  for (int cc = 0; cc < 4; cc++) {
    w0[cc] = W0_110[n * 4 + cc];
    w1[cc] = W0_110[512 + n * 4 + cc];
    w2[cc] = W0_110[1024 + n * 4 + cc];
  }
  float we0 = W0_011[512 + n * 2], we1 = W0_011[512 + n * 2 + 1];
  float bu = b0_110[n] + b0_110[128 + n] + b0_110[256 + n] + b0_011[256 + n];
  float vw00 = W0_011[n * 2], vw01 = W0_011[n * 2 + 1];
  float vw10 = W0_011[256 + n * 2], vw11 = W0_011[256 + n * 2 + 1];
  float w001 = W0_001[n];
  float bv = b0_011[n] + b0_011[128 + n] + b0_001[n];

#pragma unroll
  for (int k = 0; k < 8; k++) {
    int i = tid + k * 256, p = i >> 7, g = i & 127;
    float acc = bu + we0 * rme[g] + we1 * rme[128 + g];
#pragma unroll
    for (int cc = 0; cc < 4; cc++)
      acc += w0[cc] * xs[(cc * 16 + p) * 128 + g] + w1[cc] * rmp[cc * 128 + g]
           + w2[cc] * rmgS[cc * 16 + p];
    u0[i] = acc;
  }
  {
    const float* xa = x011 + (size_t)(b * 2) * 12288;
    const float* xb = xa + 12288;
    const float* xc = x001 + b * 96;
    for (int k = 0; k < 48; k++) {
      int i = tid + k * 256;
      int g = i / 96, e = i - g * 96;
      float val = bv + vw00 * xa[i] + vw01 * xb[i]
                + vw10 * rmg011L[e] + vw11 * rmg011L[96 + e] + w001 * xc[e];
      v0[g * 97 + e] = val;
    }
  }
  __syncthreads();
  if (tid < 128) {
    float m = -INFINITY;
    for (int p = 0; p < P; p++) m = fmaxf(m, u0[p * 128 + tid]);
    mpu[tid] = m;
    maxpU0g[bn * 128 + tid] = m;
  }
  {
    int g = tid & 127, h = tid >> 7;
    const float* r = &v0[g * 97 + h * 48];
    float m = -INFINITY;
    for (int j = 0; j < 48; j++) m = fmaxf(m, r[j]);
    part[tid] = m;
  }
  __syncthreads();
  if (tid < 128) {
    float m = fmaxf(part[tid], part[128 + tid]);
    mev[tid] = m;
    maxeV0g[bn * 128 + tid] = m;
    mp110[bn * 128 + tid] = lrelu(mpu[tid] + m);
  }
  __syncthreads();
  {
    int p = tid >> 4, ch = tid & 15;
    float m = -INFINITY;
    for (int g = ch * 8; g < ch * 8 + 8; g++)
      m = fmaxf(m, u0[p * 128 + g] + mev[g]);
    part[tid] = m;
  }
  if (tid < 96) {
    float m = -INFINITY;
    for (int g = 0; g < G; g++) m = fmaxf(m, mpu[g] + v0[g * 97 + tid]);
    s001a[bn * 96 + tid] = lrelu(m);
  }
  __syncthreads();
  if (tid < 16) {
    float m = -INFINITY;
    for (int ch = 0; ch < 16; ch++) m = fmaxf(m, part[tid * 16 + ch]);
    mg110[bn * 16 + tid] = lrelu(m);
  }
  if (n == 0) {
    for (int i = tid; i < 512; i += 256) rmpG[b * 512 + i] = rmp[i];
    if (tid < 64) rmgG[b * 64 + tid] = rmgS[tid];
    rmeG[b * 256 + tid] = rme[tid];
    if (tid < 192) rmg011G[b * 192 + tid] = rmg011L[tid];
  }
  // ---- W1 transpose/fold tail: wT[m][c][n] ----
  {
    const int gt = bn * 256 + tid;
#pragma unroll
    for (int it = 0; it < 2; it++) {
      int idx = gt + it * 65536;
      if (idx < 81920) {
        int m = idx >> 14, r = idx & 16383;
        int c = r >> 7, nn = r & 127;
        float v;
        if (m == 0)      v = W1[nn * 128 + c];
        else if (m == 1) v = W1[16384 + nn * 128 + c] + W1[5 * 16384 + nn * 128 + c];
        else if (m == 2) v = W1[2 * 16384 + nn * 128 + c];
        else if (m == 3) v = W1[3 * 16384 + nn * 128 + c];
        else             v = W1[4 * 16384 + nn * 128 + c] + W1[6 * 16384 + nn * 128 + c];
        wT[idx] = v;
      }
    }
  }
}

// ---------------------------------------------------------------------------
// K2: layer 1 PURE GEMMs. One block per (b,g), 512 threads. [R7/R8-proven]
__global__ void __launch_bounds__(512) k_layer1c(
    const float* __restrict__ x110, const float* __restrict__ x011,
    const float* __restrict__ x001,
    const float* __restrict__ W0_110, const float* __restrict__ b0_110,
    const float* __restrict__ W0_011, const float* __restrict__ b0_011,
    const float* __restrict__ W0_001, const float* __restrict__ b0_001,
    const float* __restrict__ maxpU0g, const float* __restrict__ maxeV0g,
    const float* __restrict__ rmpG, const float* __restrict__ rmgG,
    const float* __restrict__ rmeG, const float* __restrict__ rmg011G,
    const float* __restrict__ wT,
    float* __restrict__ U1, float* __restrict__ V1) {
  __shared__ float s110c[128 * 16];
  __shared__ float s011c[128 * 96];
  __shared__ float W0L110[1536], W0L011[768], W0L001[128];
  __shared__ float busum[128], bvsum[128], mpu[128], mev[128];
  __shared__ float x011row[192], rmg011s[192], x001s[96];
  __shared__ float x110col[64], rmg110p[64], rmp4[4], rme2[2];
  const int blk = blockIdx.x;
  const int b = blk >> 7, g = blk & 127;
  const int tid = threadIdx.x;

  for (int i = tid; i < 1536; i += 512) W0L110[i] = W0_110[i];
  for (int i = tid; i < 768; i += 512) W0L011[i] = W0_011[i];
  if (tid < 128) {
    W0L001[tid] = W0_001[tid];
    busum[tid] = b0_110[tid] + b0_110[128 + tid] + b0_110[256 + tid]
               + b0_011[256 + tid];
    bvsum[tid] = b0_011[tid] + b0_011[128 + tid] + b0_001[tid];
    mpu[tid] = maxpU0g[(b * 128 + tid) * 128 + g];
    mev[tid] = maxeV0g[(b * 128 + tid) * 128 + g];
  } else if (tid >= 256 && tid < 448) {
    int i = tid - 256;
    int c = i / 96, e = i % 96;
    x011row[i] = x011[((size_t)(b * 2 + c) * 128 + g) * 96 + e];
    rmg011s[i] = rmg011G[b * 192 + i];
  } else if (tid >= 448 && tid < 512) {
    int i = tid - 448;
    int c = i >> 4, p = i & 15;
    x110col[i] = x110[((size_t)(b * 4 + c) * 16 + p) * 128 + g];
    rmg110p[i] = rmgG[b * 64 + i];
  } else if (tid >= 128 && tid < 224) {
    x001s[tid - 128] = x001[b * 96 + tid - 128];
  } else if (tid >= 224 && tid < 228) {
    rmp4[tid - 224] = rmpG[(b * 4 + tid - 224) * 128 + g];
  } else if (tid >= 228 && tid < 230) {
    rme2[tid - 228] = rmeG[(b * 2 + tid - 228) * 128 + g];
  }
  __syncthreads();

#pragma unroll
  for (int k = 0; k < 4; k++) {
    int i = tid + k * 512, c = i >> 4, p = i & 15;
    float acc = busum[c] + W0L011[512 + c * 2] * rme2[0]
              + W0L011[512 + c * 2 + 1] * rme2[1];
#pragma unroll
    for (int cc = 0; cc < 4; cc++)
      acc += W0L110[c * 4 + cc] * x110col[cc * 16 + p]
           + W0L110[512 + c * 4 + cc] * rmp4[cc]
           + W0L110[1024 + c * 4 + cc] * rmg110p[cc * 16 + p];
    s110c[i] = lrelu(acc + mev[c]);
  }
  for (int k = 0; k < 24; k++) {
    int i = tid + k * 512;
    int c = i / 96, e = i - c * 96;
    float v = bvsum[c]
            + W0L011[c * 2] * x011row[e] + W0L011[c * 2 + 1] * x011row[96 + e]
            + W0L011[256 + c * 2] * rmg011s[e]
            + W0L011[256 + c * 2 + 1] * rmg011s[96 + e]
            + W0L001[c] * x001s[e];
    s011c[i] = lrelu(v + mpu[c]);
  }
  __syncthreads();

  const float* w0T = wT;
  const float* w3T = wT + 3 * 16384;

  {
    int n = tid & 127, ph = tid >> 7;
    float a[4] = {0.f, 0.f, 0.f, 0.f};
    for (int c = 0; c < 128; c++) {
      float w0v = w0T[c * 128 + n];
      float4 s = *(const float4*)&s110c[c * 16 + ph * 4];
      a[0] += w0v * s.x; a[1] += w0v * s.y; a[2] += w0v * s.z; a[3] += w0v * s.w;
    }
    float* dst = U1 + ((size_t)((b * 128 + g) * 16 + ph * 4)) * 128 + n;
#pragma unroll
    for (int j = 0; j < 4; j++) dst[j * 128] = a[j];
  }
  {
    int n0 = (tid >> 3) * 2, e0 = (tid & 7) * 12;
    float4 aA[3], aB[3];
#pragma unroll
    for (int k = 0; k < 3; k++) {
      aA[k] = make_float4(0.f, 0.f, 0.f, 0.f);
      aB[k] = make_float4(0.f, 0.f, 0.f, 0.f);
    }
    for (int c = 0; c < 128; c++) {
      float2 wv = *(const float2*)&w3T[c * 128 + n0];
      float4 s0 = *(const float4*)&s011c[c * 96 + e0];
      float4 s1 = *(const float4*)&s011c[c * 96 + e0 + 4];
      float4 s2 = *(const float4*)&s011c[c * 96 + e0 + 8];
      aA[0].x += wv.x * s0.x; aA[0].y += wv.x * s0.y;
      aA[0].z += wv.x * s0.z; aA[0].w += wv.x * s0.w;
      aA[1].x += wv.x * s1.x; aA[1].y += wv.x * s1.y;
      aA[1].z += wv.x * s1.z; aA[1].w += wv.x * s1.w;
      aA[2].x += wv.x * s2.x; aA[2].y += wv.x * s2.y;
      aA[2].z += wv.x * s2.z; aA[2].w += wv.x * s2.w;
      aB[0].x += wv.y * s0.x; aB[0].y += wv.y * s0.y;
      aB[0].z += wv.y * s0.z; aB[0].w += wv.y * s0.w;
      aB[1].x += wv.y * s1.x; aB[1].y += wv.y * s1.y;
      aB[1].z += wv.y * s1.z; aB[1].w += wv.y * s1.w;
      aB[2].x += wv.y * s2.x; aB[2].y += wv.y * s2.y;
      aB[2].z += wv.y * s2.z; aB[2].w += wv.y * s2.w;
    }
    float* dA = V1 + ((size_t)((b * 128 + g) * 128 + n0)) * 96 + e0;
    float* dB = dA + 96;
#pragma unroll
    for (int k = 0; k < 3; k++) {
      *(float4*)(dA + k * 4) = aA[k];
      *(float4*)(dB + k * 4) = aB[k];
    }
  }
}

// ---------------------------------------------------------------------------
// K3: partial g-reduction. grid = (b, nc of 8n, gc of 16g) = 256 blocks.
__global__ void __launch_bounds__(256) k_post3(
    const float* __restrict__ U1, const float* __restrict__ V1,
    const float* __restrict__ s001a, const float* __restrict__ mp110,
    const float* __restrict__ mg110,
    const float* __restrict__ wT, const float* __restrict__ b1,
    float* __restrict__ partOut) {
  constexpr int GS = 16;
  __shared__ float Vt[GS][8][100];         // 51.2KB
  __shared__ float Ut[GS][16][9];          // 9.2KB
  __shared__ float bfL[8][GS];
  __shared__ float egL[8][96];
  __shared__ float cpL[8][16];
  __shared__ float partE[GS][8][4];
  __shared__ float mxeV[GS][8], mxpU[GS][8];
  __shared__ float bbL[8], bvL[8];
  const int blk = blockIdx.x;
  const int b = blk >> 7, nc = (blk >> 3) & 15, gc = blk & 7;
  const int n0 = nc * 8, g0 = gc * 16;
  const int tid = threadIdx.x;
  const float* w15T = wT + 16384;
  const float* w2T  = wT + 2 * 16384;
  const float* w46T = wT + 4 * 16384;

  if (tid < 8) {
    int n = n0 + tid;
    bbL[tid] = b1[n] + b1[128 + n] + b1[256 + n] + b1[640 + n];
    bvL[tid] = b1[384 + n] + b1[512 + n] + b1[768 + n];
  }
  if (tid < 128) {   // bf[nn][gl] for own 16 g's
    int nn = tid >> 4, gl = tid & 15;
    float acc = 0.f;
    for (int c = 0; c < 128; c++)
      acc += w15T[c * 128 + n0 + nn] * mp110[(b * 128 + c) * 128 + g0 + gl];
    bfL[nn][gl] = acc;
  } else {           // cp[nn][p]
    int i = tid - 128;
    int nn = i >> 4, p = i & 15;
    float acc = 0.f;
    for (int c = 0; c < 128; c++)
      acc += w2T[c * 128 + n0 + nn] * mg110[(b * 128 + c) * 16 + p];
    cpL[nn][p] = acc;
  }
#pragma unroll
  for (int k = 0; k < 3; k++) {   // eg[nn][e]
    int s = tid + k * 256;
    int nn = s / 96, e = s % 96;
    float acc = 0.f;
    for (int c = 0; c < 128; c++)
      acc += w46T[c * 128 + n0 + nn] * s001a[b * 12288 + c * 96 + e];
    egL[nn][e] = acc;
  }
  __syncthreads();

  const size_t Ubase = (size_t)b * 128 * 16 * 128;
  const size_t Vbase = (size_t)b * 128 * 128 * 96;
#pragma unroll
  for (int k = 0; k < 48; k++) {   // stage V (+bv+eg): 12288 floats
    int i = tid + k * 256;
    int gs = i / 768, r = i % 768, nn = r / 96, e = r % 96;
    float v = V1[Vbase + ((size_t)(g0 + gs) * 128 + n0 + nn) * 96 + e];
    Vt[gs][nn][e] = v + bvL[nn] + egL[nn][e];
  }
#pragma unroll
  for (int k = 0; k < 8; k++) {    // stage U (+bb+cp+bf): 2048 floats
    int i = tid + k * 256;
    int gs = i >> 7, r = i & 127, p = r >> 3, nn = r & 7;
    float u = U1[Ubase + ((size_t)(g0 + gs) * 16 + p) * 128 + n0 + nn];
    Ut[gs][p][nn] = u + bbL[nn] + cpL[nn][p] + bfL[nn][gs];
  }
  __syncthreads();
#pragma unroll
  for (int k = 0; k < 2; k++) {    // partial max_e: 512 slots
    int i = tid + k * 256;
    int gs = i >> 5, nn = (i >> 2) & 7, ec = i & 3;
    float m = -INFINITY;
    for (int e = ec * 24; e < ec * 24 + 24; e++) m = fmaxf(m, Vt[gs][nn][e]);
    partE[gs][nn][ec] = m;
  }
  __syncthreads();
  if (tid < 128) {                 // finish maxes: 16gs x 8nn
    int gs = tid >> 3, nn = tid & 7;
    mxeV[gs][nn] = fmaxf(fmaxf(partE[gs][nn][0], partE[gs][nn][1]),
                         fmaxf(partE[gs][nn][2], partE[gs][nn][3]));
    float m = -INFINITY;
    for (int p = 0; p < 16; p++) m = fmaxf(m, Ut[gs][p][nn]);
    mxpU[gs][nn] = m;
  }
  __syncthreads();

  float* pb = partOut + (size_t)blk * 1664;
  if (tid < 128) {                 // pm110: item = nn*16+p = tid
    int nn = tid >> 4, p = tid & 15;
    float a = 0.f;
#pragma unroll
    for (int gs = 0; gs < GS; gs++)
      a += lrelu(Ut[gs][p][nn] + mxeV[gs][nn]);
    pb[tid] = a;
  }
#pragma unroll
  for (int k = 0; k < 3; k++) {    // psum/pmax: 768 items
    int s = tid + k * 256;
    int nn = s / 96, e = s % 96;
    float a = 0.f, m = -INFINITY;
#pragma unroll
    for (int gs = 0; gs < GS; gs++) {
      float pre = mxpU[gs][nn] + Vt[gs][nn][e];
      a += lrelu(pre);
      m = fmaxf(m, pre);
    }
    pb[128 + s] = a;
    pb[896 + s] = m;
  }
}

// ---------------------------------------------------------------------------
// K4: combine partials over 8 g-chunks. grid = (b, nc) = 32 blocks.
__global__ void __launch_bounds__(256) k_combine(
    const float* __restrict__ partIn,
    float* __restrict__ m110, float* __restrict__ m011e,
    float* __restrict__ s001b) {
  const int blk = blockIdx.x, b = blk >> 4, nc = blk & 15, n0 = nc * 8;
  const int tid = threadIdx.x;
  const float* base = partIn + (size_t)((b * 16 + nc) * 8) * 1664;
  if (tid < 128) {
    int nn = tid >> 4, p = tid & 15;
    float a = 0.f;
#pragma unroll
    for (int gc = 0; gc < 8; gc++) a += base[gc * 1664 + tid];
    m110[(b * 128 + n0 + nn) * 16 + p] = a * (1.f / G);
  }
#pragma unroll
  for (int k = 0; k < 3; k++) {
    int s = tid + k * 256;
    int nn = s / 96, e = s % 96;
    float a = 0.f, m = -INFINITY;
#pragma unroll
    for (int gc = 0; gc < 8; gc++) {
      a += base[gc * 1664 + 128 + s];
      m = fmaxf(m, base[gc * 1664 + 896 + s]);
    }
    m011e[(b * 128 + n0 + nn) * 96 + e] = a * (1.f / G);
    s001b[(b * 128 + n0 + nn) * 96 + e] = lrelu(m);
  }
}

// ---------------------------------------------------------------------------
// K5: heads, LDS-staged. One block per (b,o). [R8-proven]
__global__ void __launch_bounds__(128) k_final(const float* __restrict__ m110,
                                               const float* __restrict__ m011e,
                                               const float* __restrict__ s001,
                                               const float* __restrict__ Wact,
                                               const float* __restrict__ bact,
                                               const float* __restrict__ Wcrit,
                                               const float* __restrict__ bcrit,
                                               float* __restrict__ out) {
  __shared__ float buf[128][97];
  __shared__ float m110s[128][17];
  __shared__ float sm011[N], sm001[N], sce1[E], sce[E], scp[P], srow[P], scol[E];
  const int bo = blockIdx.x;
  const int o = bo & 1, b = bo >> 1;
  const int t = threadIdx.x;

#pragma unroll
  for (int k = 0; k < 16; k++) {
    int i = t + k * 128;
    m110s[i >> 4][i & 15] = m110[b * 2048 + i];
  }
  for (int k = 0; k < 96; k++) {
    int i = t + k * 128;
    buf[i / 96][i % 96] = m011e[b * 12288 + i];
  }
  __syncthreads();
  {
    float s = 0.f;
    for (int e = 0; e < E; e++) s += buf[t][e];
    sm011[t] = s * (1.f / E);
  }
  if (t < 96) {
    const float* wc1 = Wcrit + (1 * CO + o) * N;
    float c = 0.f;
    for (int n = 0; n < N; n++) c += wc1[n] * buf[n][t];
    sce1[t] = c;
  }
  __syncthreads();
  for (int k = 0; k < 96; k++) {
    int i = t + k * 128;
    buf[i / 96][i % 96] = s001[b * 12288 + i];
  }
  __syncthreads();
  {
    float s = 0.f;
    for (int e = 0; e < E; e++) s += buf[t][e];
    sm001[t] = s * (1.f / E);
  }
  if (t < 96) {
    const float* wc2 = Wcrit + (2 * CO + o) * N;
    float c = 0.f;
    for (int n = 0; n < N; n++) c += wc2[n] * buf[n][t];
    sce[t] = sce1[t] + c + bcrit[CO + o] + bcrit[2 * CO + o];
  }
  __syncthreads();
  if (t < P) {
    const float* wa0 = Wact + o * N;
    const float* wa1 = Wact + (1 * CO + o) * N;
    const float* wa2 = Wact + (2 * CO + o) * N;
    const float* wc0 = Wcrit + o * N;
    float a = 0.f, c = 0.f, aa = 0.f;
    for (int n = 0; n < N; n++) {
      float m = m110s[n][t];
      a += wa0[n] * m;
      c += wc0[n] * m;
      aa += wa1[n] * sm011[n] + wa2[n] * sm001[n];
    }
    float act = a + aa + bact[o] + bact[CO + o] + bact[2 * CO + o];
    out[(b * CO + o) * P + t] = lrelu(act);
    scp[t] = c + bcrit[o];
  }
  __syncthreads();
  if (t < P) {
    float m = -INFINITY;
    for (int e = 0; e < E; e++) m = fmaxf(m, lrelu(scp[t] + sce[e]));
    srow[t] = m;
  } else if (t < P + E) {
    int e = t - P;
    float m = -INFINITY;
    for (int p = 0; p < P; p++) m = fmaxf(m, lrelu(scp[p] + sce[e]));
    scol[e] = m;
  }
  __syncthreads();
  if (t == 0) {
    float v110 = 0.f, v011 = 0.f;
    for (int p = 0; p < P; p++) v110 += srow[p];
    for (int e = 0; e < E; e++) v011 += scol[e];
    out[B * CO * P + b * CO + o] = 2.f + v110 + 2.f * v011;
  }
}

extern "C" void kernel_launch(void* const* d_in, const int* in_sizes, int n_in,
                              void* d_out, int out_size, void* d_ws, size_t ws_size,
                              hipStream_t stream) {
  const float* x110   = (const float*)d_in[0];
  const float* x011   = (const float*)d_in[1];
  const float* x001   = (const float*)d_in[2];
  const float* W0_110 = (const float*)d_in[3];
  const float* b0_110 = (const float*)d_in[4];
  const float* W0_011 = (const float*)d_in[5];
  const float* b0_011 = (const float*)d_in[6];
  const float* W0_001 = (const float*)d_in[7];
  const float* b0_001 = (const float*)d_in[8];
  const float* W1     = (const float*)d_in[9];
  const float* b1     = (const float*)d_in[10];
  const float* Wact   = (const float*)d_in[11];
  const float* bact   = (const float*)d_in[12];
  const float* Wcrit  = (const float*)d_in[13];
  const float* bcrit  = (const float*)d_in[14];
  float* out = (float*)d_out;
  float* w = (float*)d_ws;

  float* U1     = w + OFF_U1;
  float* V1     = w + OFF_V1;
  float* maxpU0 = w + OFF_MAXPU0;
  float* maxeV0 = w + OFF_MAXEV0;
  float* mp110  = w + OFF_MP110;
  float* mg110  = w + OFF_MG110;
  float* s001a  = w + OFF_S001A;
  float* rmpG   = w + OFF_RMP;
  float* rmgG   = w + OFF_RMG;
  float* rmeG   = w + OFF_RME;
  float* rmg011 = w + OFF_RMG011;
  float* m110   = w + OFF_M110;
  float* m011e  = w + OFF_M011E;
  float* s001b  = w + OFF_S001B;
  float* wT     = w + OFF_WT;
  float* partB  = w + OFF_PART;

  k_layer0<<<256, 256, 0, stream>>>(x110, x011, x001, W0_110, b0_110, W0_011,
                                    b0_011, W0_001, b0_001, W1,
                                    maxpU0, maxeV0, mp110, mg110, s001a,
                                    rmpG, rmgG, rmeG, rmg011, wT);
  k_layer1c<<<256, 512, 0, stream>>>(x110, x011, x001, W0_110, b0_110, W0_011,
                                     b0_011, W0_001, b0_001,
                                     maxpU0, maxeV0, rmpG, rmgG, rmeG, rmg011,
                                     wT, U1, V1);
  k_post3<<<256, 256, 0, stream>>>(U1, V1, s001a, mp110, mg110, wT, b1, partB);
  k_combine<<<32, 256, 0, stream>>>(partB, m110, m011e, s001b);
  k_final<<<4, 128, 0, stream>>>(m110, m011e, s001b, Wact, bact, Wcrit, bcrit, out);
}